// Round 10
// baseline (151.827 us; speedup 1.0000x reference)
//
#include <hip/hip_runtime.h>

#define DIM 1024
#define NHEADS 16
#define HDIM 64
#define BATCH 2
#define SEQ 2048
#define MTOT (BATCH*SEQ)
// 1/sqrt(64) * log2(e), folded into Q so softmax uses exp2
#define QSCALE 0.18033688011112042f
#define XN ((size_t)MTOT*DIM)
#define WN ((size_t)DIM*DIM)

typedef __attribute__((ext_vector_type(8))) short short8;
typedef __attribute__((ext_vector_type(4))) float f32x4;
typedef __attribute__((ext_vector_type(16))) float f32x16;
typedef __attribute__((ext_vector_type(2))) int int2v;

static __device__ __forceinline__ unsigned short bf16rne(float f) {
    unsigned u = __builtin_bit_cast(unsigned, f);
    return (unsigned short)((u + 0x7fffu + ((u >> 16) & 1u)) >> 16);
}

// async global->LDS, 16B per lane; LDS dest must be wave-uniform (HW adds lane*16).
static __device__ __forceinline__ void gld16(const void* g, void* l) {
    __builtin_amdgcn_global_load_lds((const __attribute__((address_space(1))) void*)g,
                                     (__attribute__((address_space(3))) void*)l, 16, 0, 0);
}

static __device__ __forceinline__ f32x16 mfma32(short8 a, short8 b, f32x16 c) {
    return __builtin_amdgcn_mfma_f32_32x32x16_bf16(a, b, c, 0, 0, 0);
}

// ---------------- fused f32 -> bf16 convert of x + 4 weights ----------------
__global__ __launch_bounds__(256)
void prep(const float* __restrict__ x, const float* __restrict__ wq, const float* __restrict__ wk,
          const float* __restrict__ wv, const float* __restrict__ wo, unsigned short* __restrict__ dst)
{
    const size_t i = ((size_t)blockIdx.x*256 + threadIdx.x)*8;
    const float* s; size_t o;
    if (i < XN)           { s = x;  o = i; }
    else if (i < XN+WN)   { s = wq; o = i - XN; }
    else if (i < XN+2*WN) { s = wk; o = i - XN - WN; }
    else if (i < XN+3*WN) { s = wv; o = i - XN - 2*WN; }
    else                  { s = wo; o = i - XN - 3*WN; }
    float4 a = *(const float4*)(s + o);
    float4 b = *(const float4*)(s + o + 4);
    uint4 w;
    w.x = (unsigned)bf16rne(a.x) | ((unsigned)bf16rne(a.y) << 16);
    w.y = (unsigned)bf16rne(a.z) | ((unsigned)bf16rne(a.w) << 16);
    w.z = (unsigned)bf16rne(b.x) | ((unsigned)bf16rne(b.y) << 16);
    w.w = (unsigned)bf16rne(b.z) | ((unsigned)bf16rne(b.w) << 16);
    *(uint4*)&dst[i] = w;
}

// ---------------- fused QKV bf16 GEMM, counted-vmcnt pipeline, 3 blocks/CU ----------------
// 128x128 tile, BK=32, 256 thr (4 waves 2x2), wave tile 64x64.
// K output (widx==1) is written in ATTENTION-FRAGMENT-LINEAR layout Kp[(bh,kt)][frag][lane][8]
// so attn's global_load_lds reads contiguous 1KB per instruction (no 2x L2 request
// amplification from 2KB-strided half-line reads).
__global__ __launch_bounds__(256)
void gemm_qkv(const unsigned short* __restrict__ A,
              const unsigned short* __restrict__ W0, const unsigned short* __restrict__ W1,
              const unsigned short* __restrict__ W2,
              const float* __restrict__ b0, const float* __restrict__ b1, const float* __restrict__ b2,
              unsigned short* __restrict__ o0, unsigned short* __restrict__ o1, unsigned short* __restrict__ o2)
{
    __shared__ __align__(16) unsigned short As[3][4096];
    __shared__ __align__(16) unsigned short Bs[3][4096];
    const int t = threadIdx.x, wid = t >> 6, lane = t & 63;
    const int lr = lane & 15, lg = lane >> 4;
    const int bid = blockIdx.y * 24 + blockIdx.x;
    const int swz = (bid & 7) * 96 + (bid >> 3);
    const int sx = swz % 24, sy = swz / 24;
    const int widx = sx >> 3;
    const int n0 = (sx & 7) << 7;
    const int m0 = sy << 7;
    const unsigned short* W = widx == 0 ? W0 : (widx == 1 ? W1 : W2);
    const float* bias        = widx == 0 ? b0 : (widx == 1 ? b1 : b2);
    const float scale        = widx == 0 ? QSCALE : 1.0f;
    unsigned short* out      = widx == 0 ? o0 : (widx == 1 ? o1 : o2);

    const int wm = wid >> 1, wn = wid & 1;
    const int f0 = 2*wid, f1 = f0 + 1;
    const unsigned short* Ag0 = A + (size_t)(m0 + f0*16 + lr)*DIM + lg*8;
    const unsigned short* Ag1 = A + (size_t)(m0 + f1*16 + lr)*DIM + lg*8;
    const unsigned short* Bg0 = W + (size_t)(n0 + f0*16 + lr)*DIM + lg*8;
    const unsigned short* Bg1 = W + (size_t)(n0 + f1*16 + lr)*DIM + lg*8;

    auto stage = [&](int tt, int slot) {
        const int ko = tt * 32;
        gld16(Ag0 + ko, &As[slot][f0*512]); gld16(Ag1 + ko, &As[slot][f1*512]);
        gld16(Bg0 + ko, &Bs[slot][f0*512]); gld16(Bg1 + ko, &Bs[slot][f1*512]);
    };

    f32x4 acc[4][4] = {};
    stage(0, 0); stage(1, 1);
    int c0 = 0, c1 = 1, c2 = 2;

    for (int it = 0; it < DIM/32; ++it) {
        if (it < DIM/32 - 2) { asm volatile("s_waitcnt vmcnt(4)" ::: "memory"); }
        else                 { asm volatile("s_waitcnt vmcnt(0)" ::: "memory"); }
        __builtin_amdgcn_s_barrier();
        short8 af[4], bf[4];
        #pragma unroll
        for (int i = 0; i < 4; ++i) af[i] = *(const short8*)&As[c0][(wm*4+i)*512 + lane*8];
        #pragma unroll
        for (int i = 0; i < 4; ++i) bf[i] = *(const short8*)&Bs[c0][(wn*4+i)*512 + lane*8];
        if (it + 2 < DIM/32) stage(it + 2, c2);
        __builtin_amdgcn_s_setprio(1);
        #pragma unroll
        for (int mb = 0; mb < 4; ++mb)
            #pragma unroll
            for (int nb = 0; nb < 4; ++nb)
                acc[mb][nb] = __builtin_amdgcn_mfma_f32_16x16x32_bf16(af[mb], bf[nb], acc[mb][nb], 0, 0, 0);
        __builtin_amdgcn_s_setprio(0);
        const int tmp = c0; c0 = c1; c1 = c2; c2 = tmp;
    }

    if (widx == 1) {
        // K -> fragment-linear Kp: element (key row, h, d) ->
        // [(b*16+h)*32 + kt][frag=(s_t>>5)*4 + (d>>4)][lane=(s_t&31)|(((d>>3)&1)<<5)][e=d&7]
        #pragma unroll
        for (int nb = 0; nb < 4; ++nb) {
            const int col = n0 + wn*64 + nb*16 + lr;
            const int hh = col >> 6, dd = col & 63;
            const float bv = bias[col];
            const int fr_d = dd >> 4, ln_d = ((dd >> 3) & 1) << 5, e = dd & 7;
            #pragma unroll
            for (int mb = 0; mb < 4; ++mb) {
                #pragma unroll
                for (int j = 0; j < 4; ++j) {
                    const int row = m0 + wm*64 + mb*16 + lg*4 + j;
                    const int bb = row >> 11, s_in = row & (SEQ-1);
                    const int kt = s_in >> 6, s_t = s_in & 63;
                    const size_t off = ((size_t)((bb*NHEADS + hh)*32 + kt))*4096
                                     + ((s_t >> 5)*4 + fr_d)*512 + ((s_t & 31) | ln_d)*8 + e;
                    out[off] = bf16rne(acc[mb][nb][j] + bv);
                }
            }
        }
    } else {
        #pragma unroll
        for (int nb = 0; nb < 4; ++nb) {
            const int col = n0 + wn*64 + nb*16 + lr;
            const float bv = bias[col];
            #pragma unroll
            for (int mb = 0; mb < 4; ++mb) {
                #pragma unroll
                for (int j = 0; j < 4; ++j) {
                    const int row = m0 + wm*64 + mb*16 + lg*4 + j;
                    out[(size_t)row*DIM + col] = bf16rne((acc[mb][nb][j] + bv) * scale);
                }
            }
        }
    }
}

// ---------------- O-projection GEMM: 64x128 tile, counted-vmcnt, f32 out ----------------
__global__ __launch_bounds__(256)
void gemm_o(const unsigned short* __restrict__ A, const unsigned short* __restrict__ W,
            const float* __restrict__ bias, float* __restrict__ fo)
{
    __shared__ __align__(16) unsigned short As[3][2048];
    __shared__ __align__(16) unsigned short Bs[3][4096];
    const int t = threadIdx.x, wid = t >> 6, lane = t & 63;
    const int lr = lane & 15, lg = lane >> 4;
    const int bid = blockIdx.y * 8 + blockIdx.x;
    const int swz = (bid & 7) * 64 + (bid >> 3);
    const int n0 = (swz & 7) << 7;
    const int m0 = (swz >> 3) << 6;
    const int wm = wid >> 1, wn = wid & 1;

    const int fa = wid;
    const int g0 = 2*wid, g1 = g0 + 1;
    const unsigned short* Ag  = A + (size_t)(m0 + fa*16 + lr)*DIM + lg*8;
    const unsigned short* Bg0 = W + (size_t)(n0 + g0*16 + lr)*DIM + lg*8;
    const unsigned short* Bg1 = W + (size_t)(n0 + g1*16 + lr)*DIM + lg*8;

    auto stage = [&](int tt, int slot) {
        const int ko = tt * 32;
        gld16(Ag + ko, &As[slot][fa*512]);
        gld16(Bg0 + ko, &Bs[slot][g0*512]); gld16(Bg1 + ko, &Bs[slot][g1*512]);
    };

    f32x4 acc[2][4] = {};
    stage(0, 0); stage(1, 1);
    int c0 = 0, c1 = 1, c2 = 2;

    for (int it = 0; it < DIM/32; ++it) {
        if (it < DIM/32 - 2) { asm volatile("s_waitcnt vmcnt(3)" ::: "memory"); }
        else                 { asm volatile("s_waitcnt vmcnt(0)" ::: "memory"); }
        __builtin_amdgcn_s_barrier();
        short8 af[2], bf[4];
        #pragma unroll
        for (int i = 0; i < 2; ++i) af[i] = *(const short8*)&As[c0][(wm*2+i)*512 + lane*8];
        #pragma unroll
        for (int i = 0; i < 4; ++i) bf[i] = *(const short8*)&Bs[c0][(wn*4+i)*512 + lane*8];
        if (it + 2 < DIM/32) stage(it + 2, c2);
        __builtin_amdgcn_s_setprio(1);
        #pragma unroll
        for (int mb = 0; mb < 2; ++mb)
            #pragma unroll
            for (int nb = 0; nb < 4; ++nb)
                acc[mb][nb] = __builtin_amdgcn_mfma_f32_16x16x32_bf16(af[mb], bf[nb], acc[mb][nb], 0, 0, 0);
        __builtin_amdgcn_s_setprio(0);
        const int tmp = c0; c0 = c1; c1 = c2; c2 = tmp;
    }

    #pragma unroll
    for (int nb = 0; nb < 4; ++nb) {
        const int col = n0 + wn*64 + nb*16 + lr;
        const float bv = bias[col];
        #pragma unroll
        for (int mb = 0; mb < 2; ++mb) {
            #pragma unroll
            for (int j = 0; j < 4; ++j) {
                const int row = m0 + wm*32 + mb*16 + lg*4 + j;
                fo[(size_t)row*DIM + col] = acc[mb][nb][j] + bv;
            }
        }
    }
}

// ---------------- V pack: [b,s,h,d] -> fragment-linear Vp[(bh,kt)][frag][lane][8] ----------------
// Vp frag f, lane l, elem e = V[key kt*64 + (f&3)*16 + (l>>5)*8 + e][d (f>>2)*32 + (l&31)]
__global__ __launch_bounds__(256)
void pack_v(const unsigned short* __restrict__ V, unsigned short* __restrict__ Vp)
{
    __shared__ unsigned short tile[64][66];
    const int t  = threadIdx.x;
    const int st = blockIdx.x;
    const int bh = blockIdx.y;
    const int b = bh >> 4, h = bh & 15;
    const int sr = t >> 3;
    const int dc = (t & 7) * 8;

    #pragma unroll
    for (int r = 0; r < 2; ++r) {
        const int s = r*32 + sr;
        short8 v = *(const short8*)(V + (size_t)(b*SEQ + st*64 + s)*DIM + h*HDIM + dc);
        #pragma unroll
        for (int e = 0; e < 8; ++e) tile[s][dc + e] = (unsigned short)v[e];
    }
    __syncthreads();
    unsigned short* outb = Vp + ((size_t)bh*32 + st)*4096;
    #pragma unroll
    for (int r = 0; r < 2; ++r) {
        const int idx = t + r*256;          // (frag, lane) pair
        const int fr = idx >> 6, ln = idx & 63;
        const int s0 = (fr & 3)*16 + (ln >> 5)*8;
        const int d  = (fr >> 2)*32 + (ln & 31);
        short8 ov;
        #pragma unroll
        for (int e = 0; e < 8; ++e) ov[e] = (short)tile[s0 + e][d];
        *(short8*)(outb + fr*512 + ln*8) = ov;
    }
}

// ---------------- MFMA flash attention, 2-tile pipelined, counted vmcnt ----------------
// K/V pre-packed fragment-linear: stage() gld16s read CONTIGUOUS 1KB per instruction.
struct PA { short8 p[4]; };

static __device__ __forceinline__ PA softmax_pack(const f32x16& s0, const f32x16& s1, float& lsum) {
    float rsum = 0.f;
    unsigned pw0[4][2], pw1[4][2];
    #pragma unroll
    for (int r1 = 0; r1 < 4; ++r1)
        #pragma unroll
        for (int tt = 0; tt < 2; ++tt) {
            float pa_ = __builtin_amdgcn_exp2f(s0[4*r1+2*tt]);
            float pb_ = __builtin_amdgcn_exp2f(s0[4*r1+2*tt+1]);
            float pc_ = __builtin_amdgcn_exp2f(s1[4*r1+2*tt]);
            float pd_ = __builtin_amdgcn_exp2f(s1[4*r1+2*tt+1]);
            rsum += (pa_ + pb_) + (pc_ + pd_);
            asm("v_cvt_pk_bf16_f32 %0, %1, %2" : "=v"(pw0[r1][tt]) : "v"(pa_), "v"(pb_));
            asm("v_cvt_pk_bf16_f32 %0, %1, %2" : "=v"(pw1[r1][tt]) : "v"(pc_), "v"(pd_));
        }
    rsum += __shfl_xor(rsum, 32);
    lsum += rsum;
    PA r;
    #pragma unroll
    for (int ss = 0; ss < 4; ++ss) {
        union { short8 s8; unsigned u[4]; } pu;
        #pragma unroll
        for (int tt = 0; tt < 2; ++tt) {
            const unsigned a = (ss >> 1) ? pw1[2*(ss&1)][tt]   : pw0[2*(ss&1)][tt];
            const unsigned b = (ss >> 1) ? pw1[2*(ss&1)+1][tt] : pw0[2*(ss&1)+1][tt];
            int2v sw = __builtin_amdgcn_permlane32_swap((int)a, (int)b, false, false);
            pu.u[tt]     = (unsigned)sw[0];
            pu.u[2 + tt] = (unsigned)sw[1];
        }
        r.p[ss] = pu.s8;
    }
    return r;
}

__global__ __launch_bounds__(256)
void attn_mfma2(const unsigned short* __restrict__ Q, const unsigned short* __restrict__ Kp,
                const unsigned short* __restrict__ Vp, unsigned short* __restrict__ O)
{
    __shared__ __align__(16) unsigned short Ks[4][4096];
    __shared__ __align__(16) unsigned short Vs[4][4096];
    const int t = threadIdx.x, wid = t >> 6, lane = t & 63;
    const int l31 = lane & 31, h = lane >> 5;
    // grid (16, 32) = 512 blocks; swizzle: XCD c gets heads 4c..4c+3
    const int bid = blockIdx.y * 16 + blockIdx.x;
    const int swz = (bid & 7) * 64 + (bid >> 3);
    const int qt = swz & 15, bh = swz >> 4;
    const int b = bh >> 4, hh = bh & 15;
    const size_t qkbase = (size_t)b*SEQ*DIM + (size_t)hh*HDIM;
    const unsigned short* Qb = Q + qkbase;
    unsigned short*       Ob = O + qkbase;
    const int q0 = qt*128 + wid*32;

    short8 qf[4];   // Q as B-operand: lane holds Q[q0+l31][ds*16 + h*8 + e]
    #pragma unroll
    for (int ds = 0; ds < 4; ++ds)
        qf[ds] = *(const short8*)&Qb[(size_t)(q0 + l31)*DIM + ds*16 + h*8];

    const int f0 = 2*wid, f1 = f0 + 1;
    // frag-linear K/V: contiguous 1KB per gld16
    const unsigned short* Kg0 = Kp + (size_t)bh*32*4096 + f0*512 + lane*8;
    const unsigned short* Kg1 = Kg0 + 512;
    const unsigned short* Vg0 = Vp + (size_t)bh*32*4096 + f0*512 + lane*8;
    const unsigned short* Vg1 = Vg0 + 512;

    auto stage = [&](int tn) {   // tn < 32 guaranteed by caller
        const size_t ko = (size_t)tn * 4096;
        const int bb = tn & 3;
        gld16(Kg0 + ko, &Ks[bb][f0*512]); gld16(Kg1 + ko, &Ks[bb][f1*512]);
        gld16(Vg0 + ko, &Vs[bb][f0*512]); gld16(Vg1 + ko, &Vs[bb][f1*512]);
    };

    f32x16 ctx0 = {}, ctx1 = {};
    float lsum = 0.0f;

    stage(0); stage(1);   // 8 loads in flight

    const int NW = SEQ/128;
    for (int w = 0; w < NW; ++w) {
        const int t0 = 2*w;
        const int ba = t0 & 3, bb2 = (t0+1) & 3;
        const bool more = (w + 1 < NW);

        // B1: own stage(t0) landed (4 newest stay in flight), then block-wide
        if (more) { asm volatile("s_waitcnt vmcnt(4)" ::: "memory"); }
        else      { asm volatile("s_waitcnt vmcnt(0)" ::: "memory"); }
        __builtin_amdgcn_s_barrier();
        if (more) stage(t0 + 2);

        // QK(t0)
        f32x16 s0a = {}, s1a = {};
        __builtin_amdgcn_s_setprio(1);
        #pragma unroll
        for (int ds = 0; ds < 4; ++ds) {
            short8 kf0 = *(const short8*)&Ks[ba][ds*512 + lane*8];
            short8 kf1 = *(const short8*)&Ks[ba][(4+ds)*512 + lane*8];
            s0a = mfma32(kf0, qf[ds], s0a);
            s1a = mfma32(kf1, qf[ds], s1a);
        }
        __builtin_amdgcn_s_setprio(0);

        PA pa = softmax_pack(s0a, s1a, lsum);

        // B2: own stage(t0+1) landed; gates stage(t0+3)
        if (more) { asm volatile("s_waitcnt vmcnt(4)" ::: "memory"); }
        else      { asm volatile("s_waitcnt vmcnt(0)" ::: "memory"); }
        __builtin_amdgcn_s_barrier();
        if (more) stage(t0 + 3);

        // QK(t1)
        f32x16 s0b = {}, s1b = {};
        __builtin_amdgcn_s_setprio(1);
        #pragma unroll
        for (int ds = 0; ds < 4; ++ds) {
            short8 kf0 = *(const short8*)&Ks[bb2][ds*512 + lane*8];
            short8 kf1 = *(const short8*)&Ks[bb2][(4+ds)*512 + lane*8];
            s0b = mfma32(kf0, qf[ds], s0b);
            s1b = mfma32(kf1, qf[ds], s1b);
        }
        // PV(t0)
        #pragma unroll
        for (int ss = 0; ss < 4; ++ss) {
            short8 vf0 = *(const short8*)&Vs[ba][ss*512 + lane*8];
            short8 vf1 = *(const short8*)&Vs[ba][(4+ss)*512 + lane*8];
            ctx0 = mfma32(pa.p[ss], vf0, ctx0);
            ctx1 = mfma32(pa.p[ss], vf1, ctx1);
        }
        __builtin_amdgcn_s_setprio(0);

        PA pb = softmax_pack(s0b, s1b, lsum);

        // PV(t1)
        __builtin_amdgcn_s_setprio(1);
        #pragma unroll
        for (int ss = 0; ss < 4; ++ss) {
            short8 vf0 = *(const short8*)&Vs[bb2][ss*512 + lane*8];
            short8 vf1 = *(const short8*)&Vs[bb2][(4+ss)*512 + lane*8];
            ctx0 = mfma32(pb.p[ss], vf0, ctx0);
            ctx1 = mfma32(pb.p[ss], vf1, ctx1);
        }
        __builtin_amdgcn_s_setprio(0);
    }

    const float linv = 1.0f / lsum;
    #pragma unroll
    for (int r = 0; r < 16; ++r) {
        const int qrow = (r&3) + 8*(r>>2) + 4*h;
        const float nm = __shfl(linv, qrow);
        unsigned short* p = &Ob[(size_t)(q0 + qrow)*DIM + l31];
        p[0]  = bf16rne(ctx0[r] * nm);
        p[32] = bf16rne(ctx1[r] * nm);
    }
}

extern "C" void kernel_launch(void* const* d_in, const int* in_sizes, int n_in,
                              void* d_out, int out_size, void* d_ws, size_t ws_size,
                              hipStream_t stream) {
    const float* x  = (const float*)d_in[0];
    const float* wq = (const float*)d_in[1];
    const float* bq = (const float*)d_in[2];
    const float* wk = (const float*)d_in[3];
    const float* bk = (const float*)d_in[4];
    const float* wv = (const float*)d_in[5];
    const float* bv = (const float*)d_in[6];
    const float* wo = (const float*)d_in[7];
    const float* bo = (const float*)d_in[8];
    float* out = (float*)d_out;

    // ws (ushort): Xb/Cb 4M | Wq 1M | Wk 1M | Wv 1M | Wo 1M | Qb 4M | Kp 4M | Vb 4M | Vp 4M = 48 MB
    unsigned short* Xb  = (unsigned short*)d_ws;
    unsigned short* Wqb = Xb  + XN;
    unsigned short* Wkb = Wqb + WN;
    unsigned short* Wvb = Wkb + WN;
    unsigned short* Wob = Wvb + WN;
    unsigned short* Qb  = Wob + WN;
    unsigned short* Kpb = Qb  + XN;
    unsigned short* Vb  = Kpb + XN;
    unsigned short* Vpb = Vb  + XN;
    unsigned short* Cb  = Xb;   // attn output aliases Xb (x dead after QKV GEMM)

    prep<<<4096, 256, 0, stream>>>(x, wq, wk, wv, wo, Xb);

    gemm_qkv<<<dim3(24, 32), 256, 0, stream>>>(Xb, Wqb, Wkb, Wvb, bq, bk, bv, Qb, Kpb, Vb);

    pack_v<<<dim3(SEQ/64, BATCH*NHEADS), 256, 0, stream>>>(Vb, Vpb);
    attn_mfma2<<<dim3(SEQ/128, BATCH*NHEADS), 256, 0, stream>>>(Qb, Kpb, Vpb, Cb);

    gemm_o<<<dim3(8, 64), 256, 0, stream>>>(Cb, Wob, bo, out);
}

// Round 11
// 139.651 us; speedup vs baseline: 1.0872x; 1.0872x over previous
//
#include <hip/hip_runtime.h>

#define DIM 1024
#define NHEADS 16
#define HDIM 64
#define BATCH 2
#define SEQ 2048
#define MTOT (BATCH*SEQ)
// 1/sqrt(64) * log2(e), folded into Q so softmax uses exp2
#define QSCALE 0.18033688011112042f
#define XN ((size_t)MTOT*DIM)
#define WN ((size_t)DIM*DIM)

typedef __attribute__((ext_vector_type(8))) short short8;
typedef __attribute__((ext_vector_type(4))) float f32x4;
typedef __attribute__((ext_vector_type(16))) float f32x16;
typedef __attribute__((ext_vector_type(2))) int int2v;

static __device__ __forceinline__ unsigned short bf16rne(float f) {
    unsigned u = __builtin_bit_cast(unsigned, f);
    return (unsigned short)((u + 0x7fffu + ((u >> 16) & 1u)) >> 16);
}

// async global->LDS, 16B per lane; LDS dest must be wave-uniform (HW adds lane*16).
static __device__ __forceinline__ void gld16(const void* g, void* l) {
    __builtin_amdgcn_global_load_lds((const __attribute__((address_space(1))) void*)g,
                                     (__attribute__((address_space(3))) void*)l, 16, 0, 0);
}

static __device__ __forceinline__ f32x16 mfma32(short8 a, short8 b, f32x16 c) {
    return __builtin_amdgcn_mfma_f32_32x32x16_bf16(a, b, c, 0, 0, 0);
}

// ---------------- fused f32 -> bf16 convert of x + 4 weights ----------------
__global__ __launch_bounds__(256)
void prep(const float* __restrict__ x, const float* __restrict__ wq, const float* __restrict__ wk,
          const float* __restrict__ wv, const float* __restrict__ wo, unsigned short* __restrict__ dst)
{
    const size_t i = ((size_t)blockIdx.x*256 + threadIdx.x)*8;
    const float* s; size_t o;
    if (i < XN)           { s = x;  o = i; }
    else if (i < XN+WN)   { s = wq; o = i - XN; }
    else if (i < XN+2*WN) { s = wk; o = i - XN - WN; }
    else if (i < XN+3*WN) { s = wv; o = i - XN - 2*WN; }
    else                  { s = wo; o = i - XN - 3*WN; }
    float4 a = *(const float4*)(s + o);
    float4 b = *(const float4*)(s + o + 4);
    uint4 w;
    w.x = (unsigned)bf16rne(a.x) | ((unsigned)bf16rne(a.y) << 16);
    w.y = (unsigned)bf16rne(a.z) | ((unsigned)bf16rne(a.w) << 16);
    w.z = (unsigned)bf16rne(b.x) | ((unsigned)bf16rne(b.y) << 16);
    w.w = (unsigned)bf16rne(b.z) | ((unsigned)bf16rne(b.w) << 16);
    *(uint4*)&dst[i] = w;
}

// ---------------- fused QKV bf16 GEMM, counted-vmcnt pipeline, 3 blocks/CU ----------------
// 128x128 tile, BK=32, 256 thr (4 waves 2x2), wave tile 64x64. Row-major epilogue ONLY
// (scatter epilogues serialize the store path: proven rounds 6 & 10).
__global__ __launch_bounds__(256)
void gemm_qkv(const unsigned short* __restrict__ A,
              const unsigned short* __restrict__ W0, const unsigned short* __restrict__ W1,
              const unsigned short* __restrict__ W2,
              const float* __restrict__ b0, const float* __restrict__ b1, const float* __restrict__ b2,
              unsigned short* __restrict__ o0, unsigned short* __restrict__ o1, unsigned short* __restrict__ o2)
{
    __shared__ __align__(16) unsigned short As[3][4096];
    __shared__ __align__(16) unsigned short Bs[3][4096];
    const int t = threadIdx.x, wid = t >> 6, lane = t & 63;
    const int lr = lane & 15, lg = lane >> 4;
    const int bid = blockIdx.y * 24 + blockIdx.x;
    const int swz = (bid & 7) * 96 + (bid >> 3);
    const int sx = swz % 24, sy = swz / 24;
    const int widx = sx >> 3;
    const int n0 = (sx & 7) << 7;
    const int m0 = sy << 7;
    const unsigned short* W = widx == 0 ? W0 : (widx == 1 ? W1 : W2);
    const float* bias        = widx == 0 ? b0 : (widx == 1 ? b1 : b2);
    const float scale        = widx == 0 ? QSCALE : 1.0f;
    unsigned short* out      = widx == 0 ? o0 : (widx == 1 ? o1 : o2);

    const int wm = wid >> 1, wn = wid & 1;
    const int f0 = 2*wid, f1 = f0 + 1;
    const unsigned short* Ag0 = A + (size_t)(m0 + f0*16 + lr)*DIM + lg*8;
    const unsigned short* Ag1 = A + (size_t)(m0 + f1*16 + lr)*DIM + lg*8;
    const unsigned short* Bg0 = W + (size_t)(n0 + f0*16 + lr)*DIM + lg*8;
    const unsigned short* Bg1 = W + (size_t)(n0 + f1*16 + lr)*DIM + lg*8;

    auto stage = [&](int tt, int slot) {
        const int ko = tt * 32;
        gld16(Ag0 + ko, &As[slot][f0*512]); gld16(Ag1 + ko, &As[slot][f1*512]);
        gld16(Bg0 + ko, &Bs[slot][f0*512]); gld16(Bg1 + ko, &Bs[slot][f1*512]);
    };

    f32x4 acc[4][4] = {};
    stage(0, 0); stage(1, 1);
    int c0 = 0, c1 = 1, c2 = 2;

    for (int it = 0; it < DIM/32; ++it) {
        if (it < DIM/32 - 2) { asm volatile("s_waitcnt vmcnt(4)" ::: "memory"); }
        else                 { asm volatile("s_waitcnt vmcnt(0)" ::: "memory"); }
        __builtin_amdgcn_s_barrier();
        short8 af[4], bf[4];
        #pragma unroll
        for (int i = 0; i < 4; ++i) af[i] = *(const short8*)&As[c0][(wm*4+i)*512 + lane*8];
        #pragma unroll
        for (int i = 0; i < 4; ++i) bf[i] = *(const short8*)&Bs[c0][(wn*4+i)*512 + lane*8];
        if (it + 2 < DIM/32) stage(it + 2, c2);
        __builtin_amdgcn_s_setprio(1);
        #pragma unroll
        for (int mb = 0; mb < 4; ++mb)
            #pragma unroll
            for (int nb = 0; nb < 4; ++nb)
                acc[mb][nb] = __builtin_amdgcn_mfma_f32_16x16x32_bf16(af[mb], bf[nb], acc[mb][nb], 0, 0, 0);
        __builtin_amdgcn_s_setprio(0);
        const int tmp = c0; c0 = c1; c1 = c2; c2 = tmp;
    }

    #pragma unroll
    for (int nb = 0; nb < 4; ++nb) {
        const int col = n0 + wn*64 + nb*16 + lr;
        const float bv = bias[col];
        #pragma unroll
        for (int mb = 0; mb < 4; ++mb) {
            #pragma unroll
            for (int j = 0; j < 4; ++j) {
                const int row = m0 + wm*64 + mb*16 + lg*4 + j;
                out[(size_t)row*DIM + col] = bf16rne((acc[mb][nb][j] + bv) * scale);
            }
        }
    }
}

// ---------------- O-projection GEMM: 64x128 tile, counted-vmcnt, f32 out ----------------
__global__ __launch_bounds__(256)
void gemm_o(const unsigned short* __restrict__ A, const unsigned short* __restrict__ W,
            const float* __restrict__ bias, float* __restrict__ fo)
{
    __shared__ __align__(16) unsigned short As[3][2048];
    __shared__ __align__(16) unsigned short Bs[3][4096];
    const int t = threadIdx.x, wid = t >> 6, lane = t & 63;
    const int lr = lane & 15, lg = lane >> 4;
    const int bid = blockIdx.y * 8 + blockIdx.x;
    const int swz = (bid & 7) * 64 + (bid >> 3);
    const int n0 = (swz & 7) << 7;
    const int m0 = (swz >> 3) << 6;
    const int wm = wid >> 1, wn = wid & 1;

    const int fa = wid;
    const int g0 = 2*wid, g1 = g0 + 1;
    const unsigned short* Ag  = A + (size_t)(m0 + fa*16 + lr)*DIM + lg*8;
    const unsigned short* Bg0 = W + (size_t)(n0 + g0*16 + lr)*DIM + lg*8;
    const unsigned short* Bg1 = W + (size_t)(n0 + g1*16 + lr)*DIM + lg*8;

    auto stage = [&](int tt, int slot) {
        const int ko = tt * 32;
        gld16(Ag + ko, &As[slot][fa*512]);
        gld16(Bg0 + ko, &Bs[slot][g0*512]); gld16(Bg1 + ko, &Bs[slot][g1*512]);
    };

    f32x4 acc[2][4] = {};
    stage(0, 0); stage(1, 1);
    int c0 = 0, c1 = 1, c2 = 2;

    for (int it = 0; it < DIM/32; ++it) {
        if (it < DIM/32 - 2) { asm volatile("s_waitcnt vmcnt(3)" ::: "memory"); }
        else                 { asm volatile("s_waitcnt vmcnt(0)" ::: "memory"); }
        __builtin_amdgcn_s_barrier();
        short8 af[2], bf[4];
        #pragma unroll
        for (int i = 0; i < 2; ++i) af[i] = *(const short8*)&As[c0][(wm*2+i)*512 + lane*8];
        #pragma unroll
        for (int i = 0; i < 4; ++i) bf[i] = *(const short8*)&Bs[c0][(wn*4+i)*512 + lane*8];
        if (it + 2 < DIM/32) stage(it + 2, c2);
        __builtin_amdgcn_s_setprio(1);
        #pragma unroll
        for (int mb = 0; mb < 2; ++mb)
            #pragma unroll
            for (int nb = 0; nb < 4; ++nb)
                acc[mb][nb] = __builtin_amdgcn_mfma_f32_16x16x32_bf16(af[mb], bf[nb], acc[mb][nb], 0, 0, 0);
        __builtin_amdgcn_s_setprio(0);
        const int tmp = c0; c0 = c1; c1 = c2; c2 = tmp;
    }

    #pragma unroll
    for (int nb = 0; nb < 4; ++nb) {
        const int col = n0 + wn*64 + nb*16 + lr;
        const float bv = bias[col];
        #pragma unroll
        for (int mb = 0; mb < 2; ++mb) {
            #pragma unroll
            for (int j = 0; j < 4; ++j) {
                const int row = m0 + wm*32 + mb*16 + lg*4 + j;
                fo[(size_t)row*DIM + col] = acc[mb][nb][j] + bv;
            }
        }
    }
}

// ---------------- K/V pack: row-major -> attention-fragment-linear ----------------
// blockIdx.z: 0 = K, 1 = V. Both via LDS tile; reads AND writes fully coalesced.
// Kp frag f lane l e = K[key (f>>2)*32+(l&31)][d (f&3)*16+(l>>5)*8+e]
// Vp frag f lane l e = V[key (f&3)*16+(l>>5)*8+e][d (f>>2)*32+(l&31)]
__global__ __launch_bounds__(256)
void pack_kv(const unsigned short* __restrict__ Kg, const unsigned short* __restrict__ V,
             unsigned short* __restrict__ Kp, unsigned short* __restrict__ Vp)
{
    __shared__ unsigned short tile[64][66];
    const int t  = threadIdx.x;
    const int st = blockIdx.x;
    const int bh = blockIdx.y;
    const int isV = blockIdx.z;
    const int b = bh >> 4, h = bh & 15;
    const unsigned short* src = isV ? V : Kg;
    unsigned short* dstb = (isV ? Vp : Kp) + ((size_t)bh*32 + st)*4096;
    const int sr = t >> 3;
    const int dc = (t & 7) * 8;

    #pragma unroll
    for (int r = 0; r < 2; ++r) {
        const int s = r*32 + sr;
        short8 v = *(const short8*)(src + (size_t)(b*SEQ + st*64 + s)*DIM + h*HDIM + dc);
        #pragma unroll
        for (int e = 0; e < 8; ++e) tile[s][dc + e] = (unsigned short)v[e];
    }
    __syncthreads();
    #pragma unroll
    for (int r = 0; r < 2; ++r) {
        const int idx = t + r*256;          // (frag, lane) pair; writes contiguous
        const int fr = idx >> 6, ln = idx & 63;
        short8 ov;
        if (isV) {
            const int s0 = (fr & 3)*16 + (ln >> 5)*8;
            const int d  = (fr >> 2)*32 + (ln & 31);
            #pragma unroll
            for (int e = 0; e < 8; ++e) ov[e] = (short)tile[s0 + e][d];
        } else {
            const int key = (fr >> 2)*32 + (ln & 31);
            const int d0  = (fr & 3)*16 + (ln >> 5)*8;
            #pragma unroll
            for (int e = 0; e < 8; ++e) ov[e] = (short)tile[key][d0 + e];
        }
        *(short8*)(dstb + fr*512 + ln*8) = ov;
    }
}

// ---------------- MFMA flash attention, 2-tile pipelined, counted vmcnt ----------------
// K/V pre-packed fragment-linear: stage() gld16s read CONTIGUOUS 1KB per instruction.
struct PA { short8 p[4]; };

static __device__ __forceinline__ PA softmax_pack(const f32x16& s0, const f32x16& s1, float& lsum) {
    float rsum = 0.f;
    unsigned pw0[4][2], pw1[4][2];
    #pragma unroll
    for (int r1 = 0; r1 < 4; ++r1)
        #pragma unroll
        for (int tt = 0; tt < 2; ++tt) {
            float pa_ = __builtin_amdgcn_exp2f(s0[4*r1+2*tt]);
            float pb_ = __builtin_amdgcn_exp2f(s0[4*r1+2*tt+1]);
            float pc_ = __builtin_amdgcn_exp2f(s1[4*r1+2*tt]);
            float pd_ = __builtin_amdgcn_exp2f(s1[4*r1+2*tt+1]);
            rsum += (pa_ + pb_) + (pc_ + pd_);
            asm("v_cvt_pk_bf16_f32 %0, %1, %2" : "=v"(pw0[r1][tt]) : "v"(pa_), "v"(pb_));
            asm("v_cvt_pk_bf16_f32 %0, %1, %2" : "=v"(pw1[r1][tt]) : "v"(pc_), "v"(pd_));
        }
    rsum += __shfl_xor(rsum, 32);
    lsum += rsum;
    PA r;
    #pragma unroll
    for (int ss = 0; ss < 4; ++ss) {
        union { short8 s8; unsigned u[4]; } pu;
        #pragma unroll
        for (int tt = 0; tt < 2; ++tt) {
            const unsigned a = (ss >> 1) ? pw1[2*(ss&1)][tt]   : pw0[2*(ss&1)][tt];
            const unsigned b = (ss >> 1) ? pw1[2*(ss&1)+1][tt] : pw0[2*(ss&1)+1][tt];
            int2v sw = __builtin_amdgcn_permlane32_swap((int)a, (int)b, false, false);
            pu.u[tt]     = (unsigned)sw[0];
            pu.u[2 + tt] = (unsigned)sw[1];
        }
        r.p[ss] = pu.s8;
    }
    return r;
}

__global__ __launch_bounds__(256)
void attn_mfma2(const unsigned short* __restrict__ Q, const unsigned short* __restrict__ Kp,
                const unsigned short* __restrict__ Vp, unsigned short* __restrict__ O)
{
    __shared__ __align__(16) unsigned short Ks[4][4096];
    __shared__ __align__(16) unsigned short Vs[4][4096];
    const int t = threadIdx.x, wid = t >> 6, lane = t & 63;
    const int l31 = lane & 31, h = lane >> 5;
    // grid (16, 32) = 512 blocks; swizzle: XCD c gets heads 4c..4c+3
    const int bid = blockIdx.y * 16 + blockIdx.x;
    const int swz = (bid & 7) * 64 + (bid >> 3);
    const int qt = swz & 15, bh = swz >> 4;
    const int b = bh >> 4, hh = bh & 15;
    const size_t qkbase = (size_t)b*SEQ*DIM + (size_t)hh*HDIM;
    const unsigned short* Qb = Q + qkbase;
    unsigned short*       Ob = O + qkbase;
    const int q0 = qt*128 + wid*32;

    short8 qf[4];   // Q as B-operand: lane holds Q[q0+l31][ds*16 + h*8 + e]
    #pragma unroll
    for (int ds = 0; ds < 4; ++ds)
        qf[ds] = *(const short8*)&Qb[(size_t)(q0 + l31)*DIM + ds*16 + h*8];

    const int f0 = 2*wid, f1 = f0 + 1;
    // frag-linear K/V: contiguous 1KB per gld16
    const unsigned short* Kg0 = Kp + (size_t)bh*32*4096 + f0*512 + lane*8;
    const unsigned short* Kg1 = Kg0 + 512;
    const unsigned short* Vg0 = Vp + (size_t)bh*32*4096 + f0*512 + lane*8;
    const unsigned short* Vg1 = Vg0 + 512;

    auto stage = [&](int tn) {   // tn < 32 guaranteed by caller
        const size_t ko = (size_t)tn * 4096;
        const int bb = tn & 3;
        gld16(Kg0 + ko, &Ks[bb][f0*512]); gld16(Kg1 + ko, &Ks[bb][f1*512]);
        gld16(Vg0 + ko, &Vs[bb][f0*512]); gld16(Vg1 + ko, &Vs[bb][f1*512]);
    };

    f32x16 ctx0 = {}, ctx1 = {};
    float lsum = 0.0f;

    stage(0); stage(1);   // 8 loads in flight

    const int NW = SEQ/128;
    for (int w = 0; w < NW; ++w) {
        const int t0 = 2*w;
        const int ba = t0 & 3, bb2 = (t0+1) & 3;
        const bool more = (w + 1 < NW);

        // B1: own stage(t0) landed (4 newest stay in flight), then block-wide
        if (more) { asm volatile("s_waitcnt vmcnt(4)" ::: "memory"); }
        else      { asm volatile("s_waitcnt vmcnt(0)" ::: "memory"); }
        __builtin_amdgcn_s_barrier();
        if (more) stage(t0 + 2);

        // QK(t0)
        f32x16 s0a = {}, s1a = {};
        __builtin_amdgcn_s_setprio(1);
        #pragma unroll
        for (int ds = 0; ds < 4; ++ds) {
            short8 kf0 = *(const short8*)&Ks[ba][ds*512 + lane*8];
            short8 kf1 = *(const short8*)&Ks[ba][(4+ds)*512 + lane*8];
            s0a = mfma32(kf0, qf[ds], s0a);
            s1a = mfma32(kf1, qf[ds], s1a);
        }
        __builtin_amdgcn_s_setprio(0);

        PA pa = softmax_pack(s0a, s1a, lsum);

        // B2: own stage(t0+1) landed; gates stage(t0+3)
        if (more) { asm volatile("s_waitcnt vmcnt(4)" ::: "memory"); }
        else      { asm volatile("s_waitcnt vmcnt(0)" ::: "memory"); }
        __builtin_amdgcn_s_barrier();
        if (more) stage(t0 + 3);

        // QK(t1)
        f32x16 s0b = {}, s1b = {};
        __builtin_amdgcn_s_setprio(1);
        #pragma unroll
        for (int ds = 0; ds < 4; ++ds) {
            short8 kf0 = *(const short8*)&Ks[bb2][ds*512 + lane*8];
            short8 kf1 = *(const short8*)&Ks[bb2][(4+ds)*512 + lane*8];
            s0b = mfma32(kf0, qf[ds], s0b);
            s1b = mfma32(kf1, qf[ds], s1b);
        }
        // PV(t0)
        #pragma unroll
        for (int ss = 0; ss < 4; ++ss) {
            short8 vf0 = *(const short8*)&Vs[ba][ss*512 + lane*8];
            short8 vf1 = *(const short8*)&Vs[ba][(4+ss)*512 + lane*8];
            ctx0 = mfma32(pa.p[ss], vf0, ctx0);
            ctx1 = mfma32(pa.p[ss], vf1, ctx1);
        }
        __builtin_amdgcn_s_setprio(0);

        PA pb = softmax_pack(s0b, s1b, lsum);

        // PV(t1)
        __builtin_amdgcn_s_setprio(1);
        #pragma unroll
        for (int ss = 0; ss < 4; ++ss) {
            short8 vf0 = *(const short8*)&Vs[bb2][ss*512 + lane*8];
            short8 vf1 = *(const short8*)&Vs[bb2][(4+ss)*512 + lane*8];
            ctx0 = mfma32(pb.p[ss], vf0, ctx0);
            ctx1 = mfma32(pb.p[ss], vf1, ctx1);
        }
        __builtin_amdgcn_s_setprio(0);
    }

    const float linv = 1.0f / lsum;
    #pragma unroll
    for (int r = 0; r < 16; ++r) {
        const int qrow = (r&3) + 8*(r>>2) + 4*h;
        const float nm = __shfl(linv, qrow);
        unsigned short* p = &Ob[(size_t)(q0 + qrow)*DIM + l31];
        p[0]  = bf16rne(ctx0[r] * nm);
        p[32] = bf16rne(ctx1[r] * nm);
    }
}

extern "C" void kernel_launch(void* const* d_in, const int* in_sizes, int n_in,
                              void* d_out, int out_size, void* d_ws, size_t ws_size,
                              hipStream_t stream) {
    const float* x  = (const float*)d_in[0];
    const float* wq = (const float*)d_in[1];
    const float* bq = (const float*)d_in[2];
    const float* wk = (const float*)d_in[3];
    const float* bk = (const float*)d_in[4];
    const float* wv = (const float*)d_in[5];
    const float* bv = (const float*)d_in[6];
    const float* wo = (const float*)d_in[7];
    const float* bo = (const float*)d_in[8];
    float* out = (float*)d_out;

    // ws (ushort): Xb 4M | Wq 1M | Wk 1M | Wv 1M | Wo 1M | Qb 4M | Kb 4M | Vb 4M | Vpb 4M = 48 MB
    // Kpb aliases Xb (x dead after QKV GEMM); Cb aliases Vb (raw V dead after pack_kv).
    unsigned short* Xb  = (unsigned short*)d_ws;
    unsigned short* Wqb = Xb  + XN;
    unsigned short* Wkb = Wqb + WN;
    unsigned short* Wvb = Wkb + WN;
    unsigned short* Wob = Wvb + WN;
    unsigned short* Qb  = Wob + WN;
    unsigned short* Kb  = Qb  + XN;
    unsigned short* Vb  = Kb  + XN;
    unsigned short* Vpb = Vb  + XN;
    unsigned short* Kpb = Xb;
    unsigned short* Cb  = Vb;

    prep<<<4096, 256, 0, stream>>>(x, wq, wk, wv, wo, Xb);

    gemm_qkv<<<dim3(24, 32), 256, 0, stream>>>(Xb, Wqb, Wkb, Wvb, bq, bk, bv, Qb, Kb, Vb);

    pack_kv<<<dim3(SEQ/64, BATCH*NHEADS, 2), 256, 0, stream>>>(Kb, Vb, Kpb, Vpb);
    attn_mfma2<<<dim3(SEQ/128, BATCH*NHEADS), 256, 0, stream>>>(Qb, Kpb, Vpb, Cb);

    gemm_o<<<dim3(8, 64), 256, 0, stream>>>(Cb, Wob, bo, out);
}